// Round 12
// baseline (214.708 us; speedup 1.0000x reference)
//
#include <hip/hip_runtime.h>
#include <hip/hip_fp16.h>
#include <math.h>

#define BB 32
#define HH 512
#define WW 512
#define CC 3
#define LL 4
#define NPART 4096

typedef _Float16 h2_t __attribute__((ext_vector_type(2)));

static __device__ __forceinline__ float softplusf_(float x) {
    if (x > 20.f) return x;
    return log1pf(expf(x));
}
static __device__ __forceinline__ int iclamp_(int v, int lo, int hi) {
    return v < lo ? lo : (v > hi ? hi : v);
}

// compute one level's normalized 3x3x3 kernel into kn[27] using threads tid<3 (one per channel)
static __device__ __forceinline__ void compute_kn_(const float* __restrict__ loc,
                                                   const float* __restrict__ scale,
                                                   const float* __restrict__ eps, int lvl,
                                                   float* __restrict__ kn, int tid) {
    if (tid < 3) {
        int c = tid;
        float v[9];
        float sum = 0.f;
        #pragma unroll
        for (int t = 0; t < 9; ++t) {
            int idx = t * 3 + c;
            float s = softplusf_(scale[idx]);
            float val = loc[idx] + s * eps[lvl * 27 + idx];
            if (t == 4) val = 0.f;
            v[t] = val;
            sum += val;
        }
        float denom = sum + 1e-7f;
        #pragma unroll
        for (int t = 0; t < 9; ++t)
            kn[t * 3 + c] = v[t] / denom;
    }
}

// ---------------- horizontal downsample: fp16 planes + constant-offset dot2 ----------------
#define PSH 544
#define RESC 1.1428571428571428f

__global__ void hpass_kernel(const float* __restrict__ x, __half* __restrict__ xh2,
                             __half* __restrict__ xh4, __half* __restrict__ xh8,
                             unsigned int* __restrict__ counter) {
    __shared__ __align__(16) __half planes[4 * 3 * PSH];
    const int tid = threadIdx.x;
    const int lane = tid & 63;
    const int wv = tid >> 6;
    const int bh = blockIdx.x * 4 + wv;
    __half* pl = planes + wv * (3 * PSH);
    if (blockIdx.x == 0 && tid == 0) *counter = 0u;   // reset for fused's last-block reduction

    const float4* src = (const float4*)(x + bh * (WW * CC));
    #pragma unroll
    for (int s = 0; s < 6; ++s) {
        int i = lane + (s << 6);
        float4 v = src[i];
        int g = i << 2;
        int j = g / 3;
        int c = g - j * 3;
        float e[4] = {v.x, v.y, v.z, v.w};
        #pragma unroll
        for (int u = 0; u < 4; ++u) {
            pl[c * PSH + 17 + j] = __float2half_rn(e[u]);
            ++c;
            if (c == 3) { c = 0; ++j; }
        }
    }
    {
        int t = lane;
        if (t < 96) {
            int pp = t >> 5, k = t & 31;
            int hi = (k < 17) ? k : (512 + k);
            pl[pp * PSH + hi] = __float2half_rn(0.f);
        }
        t = lane + 64;
        if (t < 96) {
            int pp = t >> 5, k = t & 31;
            int hi = (k < 17) ? k : (512 + k);
            pl[pp * PSH + hi] = __float2half_rn(0.f);
        }
    }
    asm volatile("s_waitcnt lgkmcnt(0)" ::: "memory");

    if (xh2) {
        const h2_t P0 = {(_Float16)0.125f, (_Float16)0.375f};
        const h2_t P1 = {(_Float16)0.375f, (_Float16)0.125f};
        __half* o2 = xh2 + bh * 768;
        #pragma unroll
        for (int s = 0; s < 4; ++s) {
            int ow = lane + (s << 6);
            float res[3];
            #pragma unroll
            for (int c = 0; c < 3; ++c) {
                const __half* p = pl + c * PSH;
                int hb2 = 2 * lane + 128 * s + 16;
                h2_t v0 = *(const h2_t*)&p[hb2];
                h2_t v1 = *(const h2_t*)&p[hb2 + 2];
                float a = __builtin_amdgcn_fdot2(v0, P0, 0.f, false);
                a = __builtin_amdgcn_fdot2(v1, P1, a, false);
                res[c] = a;
            }
            if (s == 0 && lane == 0) { res[0] *= RESC; res[1] *= RESC; res[2] *= RESC; }
            if (s == 3 && lane == 63) { res[0] *= RESC; res[1] *= RESC; res[2] *= RESC; }
            o2[ow * 3 + 0] = __float2half_rn(res[0]);
            o2[ow * 3 + 1] = __float2half_rn(res[1]);
            o2[ow * 3 + 2] = __float2half_rn(res[2]);
        }
    }
    if (xh4) {
        const h2_t P0 = {(_Float16)0.f,      (_Float16)0.03125f};
        const h2_t P1 = {(_Float16)0.09375f, (_Float16)0.15625f};
        const h2_t P2 = {(_Float16)0.21875f, (_Float16)0.21875f};
        const h2_t P3 = {(_Float16)0.15625f, (_Float16)0.09375f};
        const h2_t P4 = {(_Float16)0.03125f, (_Float16)0.f};
        __half* o4 = xh4 + bh * 384;
        #pragma unroll
        for (int s = 0; s < 2; ++s) {
            int ow = lane + (s << 6);
            float res[3];
            #pragma unroll
            for (int c = 0; c < 3; ++c) {
                const __half* p = pl + c * PSH;
                int hb2 = 4 * lane + 256 * s + 14;
                float a = __builtin_amdgcn_fdot2(*(const h2_t*)&p[hb2], P0, 0.f, false);
                a = __builtin_amdgcn_fdot2(*(const h2_t*)&p[hb2 + 2], P1, a, false);
                a = __builtin_amdgcn_fdot2(*(const h2_t*)&p[hb2 + 4], P2, a, false);
                a = __builtin_amdgcn_fdot2(*(const h2_t*)&p[hb2 + 6], P3, a, false);
                a = __builtin_amdgcn_fdot2(*(const h2_t*)&p[hb2 + 8], P4, a, false);
                res[c] = a;
            }
            if (s == 0 && lane == 0) { res[0] *= RESC; res[1] *= RESC; res[2] *= RESC; }
            if (s == 1 && lane == 63) { res[0] *= RESC; res[1] *= RESC; res[2] *= RESC; }
            o4[ow * 3 + 0] = __float2half_rn(res[0]);
            o4[ow * 3 + 1] = __float2half_rn(res[1]);
            o4[ow * 3 + 2] = __float2half_rn(res[2]);
        }
    }
    if (xh8) {
        const h2_t Q0 = {(_Float16)0.f,         (_Float16)0.0078125f};
        const h2_t Q1 = {(_Float16)0.0234375f,  (_Float16)0.0390625f};
        const h2_t Q2 = {(_Float16)0.0546875f,  (_Float16)0.0703125f};
        const h2_t Q3 = {(_Float16)0.0859375f,  (_Float16)0.1015625f};
        const h2_t Q4 = {(_Float16)0.1171875f,  (_Float16)0.1171875f};
        const h2_t Q5 = {(_Float16)0.1015625f,  (_Float16)0.0859375f};
        const h2_t Q6 = {(_Float16)0.0703125f,  (_Float16)0.0546875f};
        const h2_t Q7 = {(_Float16)0.0390625f,  (_Float16)0.0234375f};
        const h2_t Q8 = {(_Float16)0.0078125f,  (_Float16)0.f};
        __half* o8 = xh8 + bh * 192;
        int ow = lane;
        float res[3];
        #pragma unroll
        for (int c = 0; c < 3; ++c) {
            const __half* p = pl + c * PSH;
            int hb2 = 8 * lane + 12;
            float a = __builtin_amdgcn_fdot2(*(const h2_t*)&p[hb2], Q0, 0.f, false);
            a = __builtin_amdgcn_fdot2(*(const h2_t*)&p[hb2 + 2], Q1, a, false);
            a = __builtin_amdgcn_fdot2(*(const h2_t*)&p[hb2 + 4], Q2, a, false);
            a = __builtin_amdgcn_fdot2(*(const h2_t*)&p[hb2 + 6], Q3, a, false);
            a = __builtin_amdgcn_fdot2(*(const h2_t*)&p[hb2 + 8], Q4, a, false);
            a = __builtin_amdgcn_fdot2(*(const h2_t*)&p[hb2 + 10], Q5, a, false);
            a = __builtin_amdgcn_fdot2(*(const h2_t*)&p[hb2 + 12], Q6, a, false);
            a = __builtin_amdgcn_fdot2(*(const h2_t*)&p[hb2 + 14], Q7, a, false);
            a = __builtin_amdgcn_fdot2(*(const h2_t*)&p[hb2 + 16], Q8, a, false);
            res[c] = a;
        }
        if (lane == 0) { res[0] *= RESC; res[1] *= RESC; res[2] *= RESC; }
        if (lane == 63) { res[0] *= RESC; res[1] *= RESC; res[2] *= RESC; }
        o8[ow * 3 + 0] = __float2half_rn(res[0]);
        o8[ow * 3 + 1] = __float2half_rn(res[1]);
        o8[ow * 3 + 2] = __float2half_rn(res[2]);
    }
}

// ---------------- per-level: LDS-staged vertical pass + conv + channel-sum ----------------
template <int F, int THB>
static __device__ __forceinline__ void level_body(const __half* __restrict__ xh,
                                                  const float* __restrict__ loc,
                                                  const float* __restrict__ scale,
                                                  const float* __restrict__ eps, int lvl,
                                                  float* __restrict__ es, int bx, int by, int b,
                                                  char* smem_raw) {
    constexpr int TH = HH / F, TW = WW / F, TW3 = TW * 3, TAPS = 2 * F;
    constexpr int RS = (THB + 3) * F;
    constexpr int DR = THB + 2;
    __half* stg = (__half*)smem_raw;                          // [RS][108]
    float* dst = (float*)(smem_raw + RS * 108 * 2);           // [DR][108]
    float* wvv = dst + DR * 108;                              // [DR][TAPS]
    float* kn = wvv + DR * TAPS;                              // [27]
    int owb = bx * 32, ohb = by * THB;
    int tid = threadIdx.x;
    compute_kn_(loc, scale, eps, lvl, kn, tid);
    if (tid >= 32 && tid < 32 + DR) {
        int r = tid - 32;
        int oh = ohb - 1 + r;
        if (oh < 0 || oh >= TH) {
            #pragma unroll
            for (int k = 0; k < TAPS; ++k) wvv[r * TAPS + k] = 0.f;
        } else {
            float sfh = (oh + 0.5f) * F - 0.5f;
            int j0 = oh * F - F / 2;
            float tmp[TAPS]; float s = 0.f;
            #pragma unroll
            for (int k = 0; k < TAPS; ++k) {
                int j = j0 + k;
                float w = (j >= 0 && j < HH) ? (1.f - fabsf(j - sfh) * (1.0f / F)) : 0.f;
                tmp[k] = w; s += w;
            }
            float inv = 1.f / s;
            #pragma unroll
            for (int k = 0; k < TAPS; ++k) wvv[r * TAPS + k] = tmp[k] * inv;
        }
    }
    int jmin = (ohb - 1) * F - F / 2;
    int cb = owb * 3 - 4;
    bool fast = (cb >= 0) && (cb + 108 <= TW3);
    const __half* xb = xh + b * (HH * TW3);
    for (int i = tid; i < RS * 27; i += 256) {
        int r = i / 27;
        int c4 = (i - r * 27) * 4;
        int jh = iclamp_(jmin + r, 0, HH - 1);
        const __half* rp = xb + jh * TW3;
        if (fast) {
            *(ushort4*)&stg[r * 108 + c4] = *(const ushort4*)(rp + cb + c4);
        } else {
            #pragma unroll
            for (int u = 0; u < 4; ++u) {
                int col = iclamp_(cb + c4 + u, 0, TW3 - 1);
                stg[r * 108 + c4 + u] = rp[col];
            }
        }
    }
    __syncthreads();
    for (int i = tid; i < DR * 27; i += 256) {
        int r = i / 27;
        int c4 = (i - r * 27) * 4;
        int gc = cb + c4;
        float v0 = 0, v1 = 0, v2 = 0, v3 = 0;
        if ((unsigned)gc < (unsigned)TW3) {
            const __half* sp = &stg[r * F * 108 + c4];
            const float* wr = &wvv[r * TAPS];
            #pragma unroll
            for (int k = 0; k < TAPS; ++k) {
                float wk = wr[k];
                const __half2* h2 = (const __half2*)(sp + k * 108);
                float2 f0 = __half22float2(h2[0]);
                float2 f1 = __half22float2(h2[1]);
                v0 += wk * f0.x; v1 += wk * f0.y;
                v2 += wk * f1.x; v3 += wk * f1.y;
            }
        }
        float4 q; q.x = v0; q.y = v1; q.z = v2; q.w = v3;
        *(float4*)&dst[r * 108 + c4] = q;
    }
    __syncthreads();
    for (int i = tid; i < THB * 32; i += 256) {
        int wl = i & 31, hl = i >> 5;
        int base = hl * 108 + wl * 3 + 1;
        float e = 0.f;
        #pragma unroll
        for (int c = 0; c < 3; ++c) {
            float conv = 0.f;
            #pragma unroll
            for (int dh = 0; dh < 3; ++dh)
                #pragma unroll
                for (int dw = 0; dw < 3; ++dw)
                    conv += kn[(dh * 3 + dw) * 3 + c] * dst[base + dh * 108 + dw * 3 + c];
            e += dst[base + 108 + 3 + c] - conv;
        }
        es[b * (TH * TW) + (ohb + hl) * TW + owb + wl] = e;
    }
}

__global__ void levels_kernel(const __half* __restrict__ xh2, const __half* __restrict__ xh4,
                              const __half* __restrict__ xh8, const float* __restrict__ loc,
                              const float* __restrict__ scale, const float* __restrict__ eps,
                              float* __restrict__ es2, float* __restrict__ es3,
                              float* __restrict__ es4, int block_base) {
    __shared__ __align__(16) char smem[16896];
    int vb = blockIdx.x + block_base;
    if (vb < 4096) {
        level_body<2, 16>(xh2, loc, scale, eps, 1, es2, vb & 7, (vb >> 3) & 15, vb >> 7, smem);
    } else if (vb < 6144) {
        int l = vb - 4096;
        level_body<4, 8>(xh4, loc, scale, eps, 2, es3, l & 3, (l >> 2) & 15, l >> 6, smem);
    } else {
        int l = vb - 6144;
        level_body<8, 4>(xh8, loc, scale, eps, 3, es4, l & 1, (l >> 1) & 15, l >> 5, smem);
    }
}

// ---------------- fused: 32x64 tile, channel planes stride 67, 8 px/thread ----------------
#define F2PS 67
#define F2PC (34 * F2PS)   // 2278
__global__ void __launch_bounds__(256, 4)
fused_kernel(const float* __restrict__ x, const float* __restrict__ loc,
             const float* __restrict__ scale, const float* __restrict__ eps,
             const float* __restrict__ es2, const float* __restrict__ es3,
             const float* __restrict__ es4, double* __restrict__ partials,
             unsigned int* __restrict__ counter, float* __restrict__ out) {
    __shared__ __align__(16) float planes[3 * F2PC];
    __shared__ float e2t[18 * 35];
    __shared__ float e3t[10 * 19];
    __shared__ float e4t[6 * 11];
    __shared__ float kn[27];
    __shared__ float smf[4];
    __shared__ double smd[4];
    int b = blockIdx.z;
    int hb = blockIdx.y * 32, wb = blockIdx.x * 64;
    int tid = threadIdx.x;
    compute_kn_(loc, scale, eps, 0, kn, tid);
    const float* xb = x + b * (HH * WW * CC);
    const int cb = wb * 3 - 3;
    const int cb2 = wb * 3 - 4;
    for (int i = tid; i < 34 * 50; i += 256) {
        int r = i / 50;
        int k = i - r * 50;
        int gh = hb - 1 + r;
        bool ghv = (unsigned)gh < (unsigned)HH;
        int g0 = cb2 + 4 * k;
        float vv[4] = {0.f, 0.f, 0.f, 0.f};
        if (ghv) {
            const float* rp = xb + gh * (WW * CC);
            if (g0 >= 0 && g0 + 4 <= WW * CC) {
                float4 v = *(const float4*)(rp + g0);
                vv[0] = v.x; vv[1] = v.y; vv[2] = v.z; vv[3] = v.w;
            } else {
                #pragma unroll
                for (int u = 0; u < 4; ++u) {
                    int g = g0 + u;
                    vv[u] = ((unsigned)g < (unsigned)(WW * CC)) ? rp[g] : 0.f;
                }
            }
        }
        #pragma unroll
        for (int u = 0; u < 4; ++u) {
            int g = g0 + u;
            if (g >= cb && g < cb + 198) {
                int gq = g + 3;
                int j = gq / 3;
                int c = gq - j * 3;
                int col = j - wb;
                planes[c * F2PC + r * F2PS + col] = vv[u];
            }
        }
    }
    {
        const float* e2b = es2 + b * (256 * 256);
        int h0 = hb / 2 - 1, w0 = wb / 2 - 1;
        for (int i = tid; i < 18 * 34; i += 256) {
            int r = i / 34, c = i - r * 34;
            int gh = iclamp_(h0 + r, 0, 255);
            int gw = iclamp_(w0 + c, 0, 255);
            e2t[r * 35 + c] = e2b[gh * 256 + gw];
        }
        const float* e3b = es3 + b * (128 * 128);
        int h03 = hb / 4 - 1, w03 = wb / 4 - 1;
        if (tid < 180) {
            int r = tid / 18, c = tid - r * 18;
            int gh = iclamp_(h03 + r, 0, 127);
            int gw = iclamp_(w03 + c, 0, 127);
            e3t[r * 19 + c] = e3b[gh * 128 + gw];
        }
        const float* e4b = es4 + b * (64 * 64);
        if (tid < 60) {
            int r = tid / 10, c = tid - r * 10;
            int gh = iclamp_(hb / 8 - 1 + r, 0, 63);
            int gw = iclamp_(wb / 8 - 1 + c, 0, 63);
            e4t[r * 11 + c] = e4b[gh * 64 + gw];
        }
    }
    __syncthreads();

    int q = tid >> 3;
    int a = tid & 7;
    float cv[8] = {0.f, 0.f, 0.f, 0.f, 0.f, 0.f, 0.f, 0.f};
    float ce[8] = {0.f, 0.f, 0.f, 0.f, 0.f, 0.f, 0.f, 0.f};
    #pragma unroll
    for (int c = 0; c < 3; ++c) {
        const float* P = planes + c * F2PC;
        #pragma unroll
        for (int dh = 0; dh < 3; ++dh) {
            const float* r0 = P + (q + dh) * F2PS + 8 * a;
            float w[10];
            #pragma unroll
            for (int t = 0; t < 10; ++t) w[t] = r0[t];
            float k0 = kn[dh * 9 + c], k1 = kn[dh * 9 + 3 + c], k2 = kn[dh * 9 + 6 + c];
            #pragma unroll
            for (int p = 0; p < 8; ++p)
                cv[p] += k0 * w[p] + k1 * w[p + 1] + k2 * w[p + 2];
            if (dh == 1) {
                #pragma unroll
                for (int p = 0; p < 8; ++p) ce[p] += w[p + 1];
            }
        }
    }
    float e[8];
    #pragma unroll
    for (int p = 0; p < 8; ++p) e[p] = ce[p] - cv[p];

    int n2 = q & 1;   float fh2 = n2 ? 0.25f : 0.75f;               int rh2 = (q >> 1) + n2;
    int n4 = q & 3;   float fh4 = ((n4 + 2) & 3) * 0.25f + 0.125f;  int rh4 = (q >> 2) + (n4 < 2 ? 0 : 1);
    int n8 = q & 7;   float fh8 = ((n8 + 4) & 7) * 0.125f + 0.0625f; int rh8 = (q >> 3) + (n8 < 4 ? 0 : 1);
    {   // L2: 6 taps per row at cols 4a..4a+5
        const float* r0 = &e2t[rh2 * 35 + 4 * a];
        const float* r1 = r0 + 35;
        float t0 = r0[0], t1 = r0[1], t2 = r0[2], t3 = r0[3], t4 = r0[4], t5 = r0[5];
        float b0 = r1[0], b1 = r1[1], b2 = r1[2], b3 = r1[3], b4 = r1[4], b5 = r1[5];
        float top, bot;
        top = t0 + 0.75f * (t1 - t0); bot = b0 + 0.75f * (b1 - b0); e[0] += top + fh2 * (bot - top);
        top = t1 + 0.25f * (t2 - t1); bot = b1 + 0.25f * (b2 - b1); e[1] += top + fh2 * (bot - top);
        top = t1 + 0.75f * (t2 - t1); bot = b1 + 0.75f * (b2 - b1); e[2] += top + fh2 * (bot - top);
        top = t2 + 0.25f * (t3 - t2); bot = b2 + 0.25f * (b3 - b2); e[3] += top + fh2 * (bot - top);
        top = t2 + 0.75f * (t3 - t2); bot = b2 + 0.75f * (b3 - b2); e[4] += top + fh2 * (bot - top);
        top = t3 + 0.25f * (t4 - t3); bot = b3 + 0.25f * (b4 - b3); e[5] += top + fh2 * (bot - top);
        top = t3 + 0.75f * (t4 - t3); bot = b3 + 0.75f * (b4 - b3); e[6] += top + fh2 * (bot - top);
        top = t4 + 0.25f * (t5 - t4); bot = b4 + 0.25f * (b5 - b4); e[7] += top + fh2 * (bot - top);
    }
    {   // L3: 4 taps per row at cols 2a..2a+3
        const float* r0 = &e3t[rh4 * 19 + 2 * a];
        const float* r1 = r0 + 19;
        float t0 = r0[0], t1 = r0[1], t2 = r0[2], t3 = r0[3];
        float b0 = r1[0], b1 = r1[1], b2 = r1[2], b3 = r1[3];
        float top, bot;
        top = t0 + 0.625f * (t1 - t0); bot = b0 + 0.625f * (b1 - b0); e[0] += top + fh4 * (bot - top);
        top = t0 + 0.875f * (t1 - t0); bot = b0 + 0.875f * (b1 - b0); e[1] += top + fh4 * (bot - top);
        top = t1 + 0.125f * (t2 - t1); bot = b1 + 0.125f * (b2 - b1); e[2] += top + fh4 * (bot - top);
        top = t1 + 0.375f * (t2 - t1); bot = b1 + 0.375f * (b2 - b1); e[3] += top + fh4 * (bot - top);
        top = t1 + 0.625f * (t2 - t1); bot = b1 + 0.625f * (b2 - b1); e[4] += top + fh4 * (bot - top);
        top = t1 + 0.875f * (t2 - t1); bot = b1 + 0.875f * (b2 - b1); e[5] += top + fh4 * (bot - top);
        top = t2 + 0.125f * (t3 - t2); bot = b2 + 0.125f * (b3 - b2); e[6] += top + fh4 * (bot - top);
        top = t2 + 0.375f * (t3 - t2); bot = b2 + 0.375f * (b3 - b2); e[7] += top + fh4 * (bot - top);
    }
    {   // L4: 3 taps per row at cols a..a+2
        const float* r0 = &e4t[rh8 * 11 + a];
        const float* r1 = r0 + 11;
        float t0 = r0[0], t1 = r0[1], t2 = r0[2];
        float b0 = r1[0], b1 = r1[1], b2 = r1[2];
        #pragma unroll
        for (int p = 0; p < 4; ++p) {
            float fw = 0.5625f + 0.125f * p;
            float top = t0 + fw * (t1 - t0);
            float bot = b0 + fw * (b1 - b0);
            e[p] += top + fh8 * (bot - top);
        }
        #pragma unroll
        for (int p = 4; p < 8; ++p) {
            float fw = 0.0625f + 0.125f * (p - 4);
            float top = t1 + fw * (t2 - t1);
            float bot = b1 + fw * (b2 - b1);
            e[p] += top + fh8 * (bot - top);
        }
    }
    float acc = 0.f;
    #pragma unroll
    for (int p = 0; p < 8; ++p) acc += e[p] * e[p];
    #pragma unroll
    for (int off = 32; off; off >>= 1) acc += __shfl_down(acc, off);
    if ((tid & 63) == 0) smf[tid >> 6] = acc;
    __syncthreads();
    if (tid == 0) {
        double s = (double)smf[0] + (double)smf[1] + (double)smf[2] + (double)smf[3];
        partials[(b * 16 + blockIdx.y) * 8 + blockIdx.x] = s;
        __threadfence();
        unsigned int old = atomicAdd(counter, 1u);
        smf[0] = (old == NPART - 1) ? 1.f : 0.f;
    }
    __syncthreads();
    if (smf[0] != 0.f) {                      // last block: global reduction + KL + output
        __threadfence();
        double facc = 0.0;
        for (int i = tid; i < NPART; i += 256) facc += partials[i];
        #pragma unroll
        for (int off = 32; off; off >>= 1) {
            facc += __shfl_down(facc, off);
        }
        if ((tid & 63) == 0) smd[tid >> 6] = facc;
        __syncthreads();
        if (tid == 0) {
            double s = smd[0] + smd[1] + smd[2] + smd[3];
            float klv = 0.f;
            for (int i = 0; i < 27; ++i) {
                float sp = softplusf_(scale[i]);
                float m = loc[i];
                klv += -logf(sp) + 0.5f * (sp * sp + m * m) - 0.5f;
            }
            out[0] = (float)(s / (double)BB + (double)LL * (double)klv);
        }
    }
}

extern "C" void kernel_launch(void* const* d_in, const int* in_sizes, int n_in,
                              void* d_out, int out_size, void* d_ws, size_t ws_size,
                              hipStream_t stream) {
    const float* x = (const float*)d_in[0];
    const float* loc = (const float*)d_in[1];
    const float* scale = (const float*)d_in[2];
    const float* eps = (const float*)d_in[3];
    float* out = (float*)d_out;

    char* ws = (char*)d_ws;
    double* partials = (double*)(ws + 1024);          // 4096*8 -> ends 33792
    unsigned int* counter = (unsigned int*)(ws + 65536);
    float* es4 = (float*)(ws + 131072);               // 524288  -> 655360
    float* es3 = (float*)(ws + 655360);               // 2097152 -> 2752512
    float* es2 = (float*)(ws + 2752512);              // 8388608 -> 11141120
    (void)in_sizes; (void)n_in; (void)out_size;

    const size_t SINGLE_NEED = 55181312ull;
    if (ws_size >= SINGLE_NEED) {
        __half* xh2 = (__half*)(ws + 11141120);       // 25165824 -> 36306944
        __half* xh4 = (__half*)(ws + 36306944);       // 12582912 -> 48889856
        __half* xh8 = (__half*)(ws + 48889856);       // 6291456  -> 55181312
        hpass_kernel<<<BB * HH / 4, 256, 0, stream>>>(x, xh2, xh4, xh8, counter);
        levels_kernel<<<7168, 256, 0, stream>>>(xh2, xh4, xh8, loc, scale, eps, es2, es3, es4, 0);
    } else {
        __half* xh4 = (__half*)(ws + 11141120);
        __half* xh8 = (__half*)(ws + 23724032);
        __half* xh2 = (__half*)(ws + 11141120);
        hpass_kernel<<<BB * HH / 4, 256, 0, stream>>>(x, nullptr, xh4, xh8, counter);
        levels_kernel<<<3072, 256, 0, stream>>>(nullptr, xh4, xh8, loc, scale, eps, es2, es3, es4, 4096);
        hpass_kernel<<<BB * HH / 4, 256, 0, stream>>>(x, xh2, nullptr, nullptr, counter);
        levels_kernel<<<4096, 256, 0, stream>>>(xh2, nullptr, nullptr, loc, scale, eps, es2, es3, es4, 0);
    }

    fused_kernel<<<dim3(8, 16, BB), 256, 0, stream>>>(x, loc, scale, eps, es2, es3, es4,
                                                      partials, counter, out);
}

// Round 13
// 137.982 us; speedup vs baseline: 1.5561x; 1.5561x over previous
//
#include <hip/hip_runtime.h>
#include <hip/hip_fp16.h>
#include <math.h>

#define BB 32
#define HH 512
#define WW 512
#define CC 3
#define LL 4

typedef _Float16 h2_t __attribute__((ext_vector_type(2)));

static __device__ __forceinline__ float softplusf_(float x) {
    if (x > 20.f) return x;
    return log1pf(expf(x));
}
static __device__ __forceinline__ int iclamp_(int v, int lo, int hi) {
    return v < lo ? lo : (v > hi ? hi : v);
}

// compute one level's normalized 3x3x3 kernel into kn[27] (threads tid<3, one per channel)
static __device__ __forceinline__ void compute_kn_(const float* __restrict__ loc,
                                                   const float* __restrict__ scale,
                                                   const float* __restrict__ eps, int lvl,
                                                   float* __restrict__ kn, int tid) {
    if (tid < 3) {
        int c = tid;
        float v[9];
        float sum = 0.f;
        #pragma unroll
        for (int t = 0; t < 9; ++t) {
            int idx = t * 3 + c;
            float s = softplusf_(scale[idx]);
            float val = loc[idx] + s * eps[lvl * 27 + idx];
            if (t == 4) val = 0.f;
            v[t] = val;
            sum += val;
        }
        float denom = sum + 1e-7f;
        #pragma unroll
        for (int t = 0; t < 9; ++t)
            kn[t * 3 + c] = v[t] / denom;
    }
}

// ---------------- horizontal downsample: fp16 planes + constant-offset dot2 ----------------
#define PSH 544
#define RESC 1.1428571428571428f

__global__ void hpass_kernel(const float* __restrict__ x, __half* __restrict__ xh2,
                             __half* __restrict__ xh4, __half* __restrict__ xh8) {
    __shared__ __align__(16) __half planes[4 * 3 * PSH];
    const int tid = threadIdx.x;
    const int lane = tid & 63;
    const int wv = tid >> 6;
    const int bh = blockIdx.x * 4 + wv;
    __half* pl = planes + wv * (3 * PSH);

    const float4* src = (const float4*)(x + bh * (WW * CC));
    #pragma unroll
    for (int s = 0; s < 6; ++s) {
        int i = lane + (s << 6);
        float4 v = src[i];
        int g = i << 2;
        int j = g / 3;
        int c = g - j * 3;
        float e[4] = {v.x, v.y, v.z, v.w};
        #pragma unroll
        for (int u = 0; u < 4; ++u) {
            pl[c * PSH + 17 + j] = __float2half_rn(e[u]);
            ++c;
            if (c == 3) { c = 0; ++j; }
        }
    }
    {
        int t = lane;
        if (t < 96) {
            int pp = t >> 5, k = t & 31;
            int hi = (k < 17) ? k : (512 + k);
            pl[pp * PSH + hi] = __float2half_rn(0.f);
        }
        t = lane + 64;
        if (t < 96) {
            int pp = t >> 5, k = t & 31;
            int hi = (k < 17) ? k : (512 + k);
            pl[pp * PSH + hi] = __float2half_rn(0.f);
        }
    }
    asm volatile("s_waitcnt lgkmcnt(0)" ::: "memory");

    if (xh2) {
        const h2_t P0 = {(_Float16)0.125f, (_Float16)0.375f};
        const h2_t P1 = {(_Float16)0.375f, (_Float16)0.125f};
        __half* o2 = xh2 + bh * 768;
        #pragma unroll
        for (int s = 0; s < 4; ++s) {
            int ow = lane + (s << 6);
            float res[3];
            #pragma unroll
            for (int c = 0; c < 3; ++c) {
                const __half* p = pl + c * PSH;
                int hb2 = 2 * lane + 128 * s + 16;
                h2_t v0 = *(const h2_t*)&p[hb2];
                h2_t v1 = *(const h2_t*)&p[hb2 + 2];
                float a = __builtin_amdgcn_fdot2(v0, P0, 0.f, false);
                a = __builtin_amdgcn_fdot2(v1, P1, a, false);
                res[c] = a;
            }
            if (s == 0 && lane == 0) { res[0] *= RESC; res[1] *= RESC; res[2] *= RESC; }
            if (s == 3 && lane == 63) { res[0] *= RESC; res[1] *= RESC; res[2] *= RESC; }
            o2[ow * 3 + 0] = __float2half_rn(res[0]);
            o2[ow * 3 + 1] = __float2half_rn(res[1]);
            o2[ow * 3 + 2] = __float2half_rn(res[2]);
        }
    }
    if (xh4) {
        const h2_t P0 = {(_Float16)0.f,      (_Float16)0.03125f};
        const h2_t P1 = {(_Float16)0.09375f, (_Float16)0.15625f};
        const h2_t P2 = {(_Float16)0.21875f, (_Float16)0.21875f};
        const h2_t P3 = {(_Float16)0.15625f, (_Float16)0.09375f};
        const h2_t P4 = {(_Float16)0.03125f, (_Float16)0.f};
        __half* o4 = xh4 + bh * 384;
        #pragma unroll
        for (int s = 0; s < 2; ++s) {
            int ow = lane + (s << 6);
            float res[3];
            #pragma unroll
            for (int c = 0; c < 3; ++c) {
                const __half* p = pl + c * PSH;
                int hb2 = 4 * lane + 256 * s + 14;
                float a = __builtin_amdgcn_fdot2(*(const h2_t*)&p[hb2], P0, 0.f, false);
                a = __builtin_amdgcn_fdot2(*(const h2_t*)&p[hb2 + 2], P1, a, false);
                a = __builtin_amdgcn_fdot2(*(const h2_t*)&p[hb2 + 4], P2, a, false);
                a = __builtin_amdgcn_fdot2(*(const h2_t*)&p[hb2 + 6], P3, a, false);
                a = __builtin_amdgcn_fdot2(*(const h2_t*)&p[hb2 + 8], P4, a, false);
                res[c] = a;
            }
            if (s == 0 && lane == 0) { res[0] *= RESC; res[1] *= RESC; res[2] *= RESC; }
            if (s == 1 && lane == 63) { res[0] *= RESC; res[1] *= RESC; res[2] *= RESC; }
            o4[ow * 3 + 0] = __float2half_rn(res[0]);
            o4[ow * 3 + 1] = __float2half_rn(res[1]);
            o4[ow * 3 + 2] = __float2half_rn(res[2]);
        }
    }
    if (xh8) {
        const h2_t Q0 = {(_Float16)0.f,         (_Float16)0.0078125f};
        const h2_t Q1 = {(_Float16)0.0234375f,  (_Float16)0.0390625f};
        const h2_t Q2 = {(_Float16)0.0546875f,  (_Float16)0.0703125f};
        const h2_t Q3 = {(_Float16)0.0859375f,  (_Float16)0.1015625f};
        const h2_t Q4 = {(_Float16)0.1171875f,  (_Float16)0.1171875f};
        const h2_t Q5 = {(_Float16)0.1015625f,  (_Float16)0.0859375f};
        const h2_t Q6 = {(_Float16)0.0703125f,  (_Float16)0.0546875f};
        const h2_t Q7 = {(_Float16)0.0390625f,  (_Float16)0.0234375f};
        const h2_t Q8 = {(_Float16)0.0078125f,  (_Float16)0.f};
        __half* o8 = xh8 + bh * 192;
        int ow = lane;
        float res[3];
        #pragma unroll
        for (int c = 0; c < 3; ++c) {
            const __half* p = pl + c * PSH;
            int hb2 = 8 * lane + 12;
            float a = __builtin_amdgcn_fdot2(*(const h2_t*)&p[hb2], Q0, 0.f, false);
            a = __builtin_amdgcn_fdot2(*(const h2_t*)&p[hb2 + 2], Q1, a, false);
            a = __builtin_amdgcn_fdot2(*(const h2_t*)&p[hb2 + 4], Q2, a, false);
            a = __builtin_amdgcn_fdot2(*(const h2_t*)&p[hb2 + 6], Q3, a, false);
            a = __builtin_amdgcn_fdot2(*(const h2_t*)&p[hb2 + 8], Q4, a, false);
            a = __builtin_amdgcn_fdot2(*(const h2_t*)&p[hb2 + 10], Q5, a, false);
            a = __builtin_amdgcn_fdot2(*(const h2_t*)&p[hb2 + 12], Q6, a, false);
            a = __builtin_amdgcn_fdot2(*(const h2_t*)&p[hb2 + 14], Q7, a, false);
            a = __builtin_amdgcn_fdot2(*(const h2_t*)&p[hb2 + 16], Q8, a, false);
            res[c] = a;
        }
        if (lane == 0) { res[0] *= RESC; res[1] *= RESC; res[2] *= RESC; }
        if (lane == 63) { res[0] *= RESC; res[1] *= RESC; res[2] *= RESC; }
        o8[ow * 3 + 0] = __float2half_rn(res[0]);
        o8[ow * 3 + 1] = __float2half_rn(res[1]);
        o8[ow * 3 + 2] = __float2half_rn(res[2]);
    }
}

// ---------------- per-level: LDS-staged vertical pass + conv + channel-sum ----------------
template <int F, int THB>
static __device__ __forceinline__ void level_body(const __half* __restrict__ xh,
                                                  const float* __restrict__ loc,
                                                  const float* __restrict__ scale,
                                                  const float* __restrict__ eps, int lvl,
                                                  float* __restrict__ es, int bx, int by, int b,
                                                  char* smem_raw) {
    constexpr int TH = HH / F, TW = WW / F, TW3 = TW * 3, TAPS = 2 * F;
    constexpr int RS = (THB + 3) * F;
    constexpr int DR = THB + 2;
    __half* stg = (__half*)smem_raw;                          // [RS][108]
    float* dst = (float*)(smem_raw + RS * 108 * 2);           // [DR][108]
    float* wvv = dst + DR * 108;                              // [DR][TAPS]
    float* kn = wvv + DR * TAPS;                              // [27]
    int owb = bx * 32, ohb = by * THB;
    int tid = threadIdx.x;
    compute_kn_(loc, scale, eps, lvl, kn, tid);
    if (tid >= 32 && tid < 32 + DR) {
        int r = tid - 32;
        int oh = ohb - 1 + r;
        if (oh < 0 || oh >= TH) {
            #pragma unroll
            for (int k = 0; k < TAPS; ++k) wvv[r * TAPS + k] = 0.f;
        } else {
            float sfh = (oh + 0.5f) * F - 0.5f;
            int j0 = oh * F - F / 2;
            float tmp[TAPS]; float s = 0.f;
            #pragma unroll
            for (int k = 0; k < TAPS; ++k) {
                int j = j0 + k;
                float w = (j >= 0 && j < HH) ? (1.f - fabsf(j - sfh) * (1.0f / F)) : 0.f;
                tmp[k] = w; s += w;
            }
            float inv = 1.f / s;
            #pragma unroll
            for (int k = 0; k < TAPS; ++k) wvv[r * TAPS + k] = tmp[k] * inv;
        }
    }
    int jmin = (ohb - 1) * F - F / 2;
    int cb = owb * 3 - 4;
    bool fast = (cb >= 0) && (cb + 108 <= TW3);
    const __half* xb = xh + b * (HH * TW3);
    for (int i = tid; i < RS * 27; i += 256) {
        int r = i / 27;
        int c4 = (i - r * 27) * 4;
        int jh = iclamp_(jmin + r, 0, HH - 1);
        const __half* rp = xb + jh * TW3;
        if (fast) {
            *(ushort4*)&stg[r * 108 + c4] = *(const ushort4*)(rp + cb + c4);
        } else {
            #pragma unroll
            for (int u = 0; u < 4; ++u) {
                int col = iclamp_(cb + c4 + u, 0, TW3 - 1);
                stg[r * 108 + c4 + u] = rp[col];
            }
        }
    }
    __syncthreads();
    for (int i = tid; i < DR * 27; i += 256) {
        int r = i / 27;
        int c4 = (i - r * 27) * 4;
        int gc = cb + c4;
        float v0 = 0, v1 = 0, v2 = 0, v3 = 0;
        if ((unsigned)gc < (unsigned)TW3) {
            const __half* sp = &stg[r * F * 108 + c4];
            const float* wr = &wvv[r * TAPS];
            #pragma unroll
            for (int k = 0; k < TAPS; ++k) {
                float wk = wr[k];
                const __half2* h2 = (const __half2*)(sp + k * 108);
                float2 f0 = __half22float2(h2[0]);
                float2 f1 = __half22float2(h2[1]);
                v0 += wk * f0.x; v1 += wk * f0.y;
                v2 += wk * f1.x; v3 += wk * f1.y;
            }
        }
        float4 q; q.x = v0; q.y = v1; q.z = v2; q.w = v3;
        *(float4*)&dst[r * 108 + c4] = q;
    }
    __syncthreads();
    for (int i = tid; i < THB * 32; i += 256) {
        int wl = i & 31, hl = i >> 5;
        int base = hl * 108 + wl * 3 + 1;
        float e = 0.f;
        #pragma unroll
        for (int c = 0; c < 3; ++c) {
            float conv = 0.f;
            #pragma unroll
            for (int dh = 0; dh < 3; ++dh)
                #pragma unroll
                for (int dw = 0; dw < 3; ++dw)
                    conv += kn[(dh * 3 + dw) * 3 + c] * dst[base + dh * 108 + dw * 3 + c];
            e += dst[base + 108 + 3 + c] - conv;
        }
        es[b * (TH * TW) + (ohb + hl) * TW + owb + wl] = e;
    }
}

__global__ void levels_kernel(const __half* __restrict__ xh2, const __half* __restrict__ xh4,
                              const __half* __restrict__ xh8, const float* __restrict__ loc,
                              const float* __restrict__ scale, const float* __restrict__ eps,
                              float* __restrict__ es2, float* __restrict__ es3,
                              float* __restrict__ es4, int block_base) {
    __shared__ __align__(16) char smem[16896];
    int vb = blockIdx.x + block_base;
    if (vb < 4096) {
        level_body<2, 16>(xh2, loc, scale, eps, 1, es2, vb & 7, (vb >> 3) & 15, vb >> 7, smem);
    } else if (vb < 6144) {
        int l = vb - 4096;
        level_body<4, 8>(xh4, loc, scale, eps, 2, es3, l & 3, (l >> 2) & 15, l >> 6, smem);
    } else {
        int l = vb - 6144;
        level_body<8, 4>(xh8, loc, scale, eps, 3, es4, l & 1, (l >> 1) & 15, l >> 5, smem);
    }
}

// ---------------- fused: 32x64 tile, channel planes stride 67, 8 px/thread ----------------
#define F2PS 67
#define F2PC (34 * F2PS)   // 2278
__global__ void __launch_bounds__(256, 4)
fused_kernel(const float* __restrict__ x, const float* __restrict__ loc,
             const float* __restrict__ scale, const float* __restrict__ eps,
             const float* __restrict__ es2, const float* __restrict__ es3,
             const float* __restrict__ es4, double* __restrict__ partials) {
    __shared__ __align__(16) float planes[3 * F2PC];
    __shared__ float e2t[18 * 35];
    __shared__ float e3t[10 * 19];
    __shared__ float e4t[6 * 11];
    __shared__ float kn[27];
    __shared__ float smf[4];
    int b = blockIdx.z;
    int hb = blockIdx.y * 32, wb = blockIdx.x * 64;
    int tid = threadIdx.x;
    compute_kn_(loc, scale, eps, 0, kn, tid);
    const float* xb = x + b * (HH * WW * CC);
    const int cb = wb * 3 - 3;
    const int cb2 = wb * 3 - 4;
    for (int i = tid; i < 34 * 50; i += 256) {
        int r = i / 50;
        int k = i - r * 50;
        int gh = hb - 1 + r;
        bool ghv = (unsigned)gh < (unsigned)HH;
        int g0 = cb2 + 4 * k;
        float vv[4] = {0.f, 0.f, 0.f, 0.f};
        if (ghv) {
            const float* rp = xb + gh * (WW * CC);
            if (g0 >= 0 && g0 + 4 <= WW * CC) {
                float4 v = *(const float4*)(rp + g0);
                vv[0] = v.x; vv[1] = v.y; vv[2] = v.z; vv[3] = v.w;
            } else {
                #pragma unroll
                for (int u = 0; u < 4; ++u) {
                    int g = g0 + u;
                    vv[u] = ((unsigned)g < (unsigned)(WW * CC)) ? rp[g] : 0.f;
                }
            }
        }
        #pragma unroll
        for (int u = 0; u < 4; ++u) {
            int g = g0 + u;
            if (g >= cb && g < cb + 198) {
                int gq = g + 3;
                int j = gq / 3;
                int c = gq - j * 3;
                int col = j - wb;
                planes[c * F2PC + r * F2PS + col] = vv[u];
            }
        }
    }
    {
        const float* e2b = es2 + b * (256 * 256);
        int h0 = hb / 2 - 1, w0 = wb / 2 - 1;
        for (int i = tid; i < 18 * 34; i += 256) {
            int r = i / 34, c = i - r * 34;
            int gh = iclamp_(h0 + r, 0, 255);
            int gw = iclamp_(w0 + c, 0, 255);
            e2t[r * 35 + c] = e2b[gh * 256 + gw];
        }
        const float* e3b = es3 + b * (128 * 128);
        int h03 = hb / 4 - 1, w03 = wb / 4 - 1;
        if (tid < 180) {
            int r = tid / 18, c = tid - r * 18;
            int gh = iclamp_(h03 + r, 0, 127);
            int gw = iclamp_(w03 + c, 0, 127);
            e3t[r * 19 + c] = e3b[gh * 128 + gw];
        }
        const float* e4b = es4 + b * (64 * 64);
        if (tid < 60) {
            int r = tid / 10, c = tid - r * 10;
            int gh = iclamp_(hb / 8 - 1 + r, 0, 63);
            int gw = iclamp_(wb / 8 - 1 + c, 0, 63);
            e4t[r * 11 + c] = e4b[gh * 64 + gw];
        }
    }
    __syncthreads();

    int q = tid >> 3;
    int a = tid & 7;
    float cv[8] = {0.f, 0.f, 0.f, 0.f, 0.f, 0.f, 0.f, 0.f};
    float ce[8] = {0.f, 0.f, 0.f, 0.f, 0.f, 0.f, 0.f, 0.f};
    #pragma unroll
    for (int c = 0; c < 3; ++c) {
        const float* P = planes + c * F2PC;
        #pragma unroll
        for (int dh = 0; dh < 3; ++dh) {
            const float* r0 = P + (q + dh) * F2PS + 8 * a;
            float w[10];
            #pragma unroll
            for (int t = 0; t < 10; ++t) w[t] = r0[t];
            float k0 = kn[dh * 9 + c], k1 = kn[dh * 9 + 3 + c], k2 = kn[dh * 9 + 6 + c];
            #pragma unroll
            for (int p = 0; p < 8; ++p)
                cv[p] += k0 * w[p] + k1 * w[p + 1] + k2 * w[p + 2];
            if (dh == 1) {
                #pragma unroll
                for (int p = 0; p < 8; ++p) ce[p] += w[p + 1];
            }
        }
    }
    float e[8];
    #pragma unroll
    for (int p = 0; p < 8; ++p) e[p] = ce[p] - cv[p];

    int n2 = q & 1;   float fh2 = n2 ? 0.25f : 0.75f;               int rh2 = (q >> 1) + n2;
    int n4 = q & 3;   float fh4 = ((n4 + 2) & 3) * 0.25f + 0.125f;  int rh4 = (q >> 2) + (n4 < 2 ? 0 : 1);
    int n8 = q & 7;   float fh8 = ((n8 + 4) & 7) * 0.125f + 0.0625f; int rh8 = (q >> 3) + (n8 < 4 ? 0 : 1);
    {   // L2: 6 taps per row at cols 4a..4a+5
        const float* r0 = &e2t[rh2 * 35 + 4 * a];
        const float* r1 = r0 + 35;
        float t0 = r0[0], t1 = r0[1], t2 = r0[2], t3 = r0[3], t4 = r0[4], t5 = r0[5];
        float b0 = r1[0], b1 = r1[1], b2 = r1[2], b3 = r1[3], b4 = r1[4], b5 = r1[5];
        float top, bot;
        top = t0 + 0.75f * (t1 - t0); bot = b0 + 0.75f * (b1 - b0); e[0] += top + fh2 * (bot - top);
        top = t1 + 0.25f * (t2 - t1); bot = b1 + 0.25f * (b2 - b1); e[1] += top + fh2 * (bot - top);
        top = t1 + 0.75f * (t2 - t1); bot = b1 + 0.75f * (b2 - b1); e[2] += top + fh2 * (bot - top);
        top = t2 + 0.25f * (t3 - t2); bot = b2 + 0.25f * (b3 - b2); e[3] += top + fh2 * (bot - top);
        top = t2 + 0.75f * (t3 - t2); bot = b2 + 0.75f * (b3 - b2); e[4] += top + fh2 * (bot - top);
        top = t3 + 0.25f * (t4 - t3); bot = b3 + 0.25f * (b4 - b3); e[5] += top + fh2 * (bot - top);
        top = t3 + 0.75f * (t4 - t3); bot = b3 + 0.75f * (b4 - b3); e[6] += top + fh2 * (bot - top);
        top = t4 + 0.25f * (t5 - t4); bot = b4 + 0.25f * (b5 - b4); e[7] += top + fh2 * (bot - top);
    }
    {   // L3: 4 taps per row at cols 2a..2a+3
        const float* r0 = &e3t[rh4 * 19 + 2 * a];
        const float* r1 = r0 + 19;
        float t0 = r0[0], t1 = r0[1], t2 = r0[2], t3 = r0[3];
        float b0 = r1[0], b1 = r1[1], b2 = r1[2], b3 = r1[3];
        float top, bot;
        top = t0 + 0.625f * (t1 - t0); bot = b0 + 0.625f * (b1 - b0); e[0] += top + fh4 * (bot - top);
        top = t0 + 0.875f * (t1 - t0); bot = b0 + 0.875f * (b1 - b0); e[1] += top + fh4 * (bot - top);
        top = t1 + 0.125f * (t2 - t1); bot = b1 + 0.125f * (b2 - b1); e[2] += top + fh4 * (bot - top);
        top = t1 + 0.375f * (t2 - t1); bot = b1 + 0.375f * (b2 - b1); e[3] += top + fh4 * (bot - top);
        top = t1 + 0.625f * (t2 - t1); bot = b1 + 0.625f * (b2 - b1); e[4] += top + fh4 * (bot - top);
        top = t1 + 0.875f * (t2 - t1); bot = b1 + 0.875f * (b2 - b1); e[5] += top + fh4 * (bot - top);
        top = t2 + 0.125f * (t3 - t2); bot = b2 + 0.125f * (b3 - b2); e[6] += top + fh4 * (bot - top);
        top = t2 + 0.375f * (t3 - t2); bot = b2 + 0.375f * (b3 - b2); e[7] += top + fh4 * (bot - top);
    }
    {   // L4: 3 taps per row at cols a..a+2
        const float* r0 = &e4t[rh8 * 11 + a];
        const float* r1 = r0 + 11;
        float t0 = r0[0], t1 = r0[1], t2 = r0[2];
        float b0 = r1[0], b1 = r1[1], b2 = r1[2];
        #pragma unroll
        for (int p = 0; p < 4; ++p) {
            float fw = 0.5625f + 0.125f * p;
            float top = t0 + fw * (t1 - t0);
            float bot = b0 + fw * (b1 - b0);
            e[p] += top + fh8 * (bot - top);
        }
        #pragma unroll
        for (int p = 4; p < 8; ++p) {
            float fw = 0.0625f + 0.125f * (p - 4);
            float top = t1 + fw * (t2 - t1);
            float bot = b1 + fw * (b2 - b1);
            e[p] += top + fh8 * (bot - top);
        }
    }
    float acc = 0.f;
    #pragma unroll
    for (int p = 0; p < 8; ++p) acc += e[p] * e[p];
    #pragma unroll
    for (int off = 32; off; off >>= 1) acc += __shfl_down(acc, off);
    if ((tid & 63) == 0) smf[tid >> 6] = acc;
    __syncthreads();
    if (tid == 0) {
        double s = (double)smf[0] + (double)smf[1] + (double)smf[2] + (double)smf[3];
        partials[(b * 16 + blockIdx.y) * 8 + blockIdx.x] = s;
    }
}

__global__ void final_kernel(const double* __restrict__ partials, int n,
                             const float* __restrict__ loc, const float* __restrict__ scale,
                             float* __restrict__ out) {
    __shared__ double sm[1024];
    double acc = 0.0;
    for (int i = threadIdx.x; i < n; i += 1024) acc += partials[i];
    sm[threadIdx.x] = acc;
    __syncthreads();
    for (int s = 512; s > 0; s >>= 1) {
        if (threadIdx.x < (unsigned)s) sm[threadIdx.x] += sm[threadIdx.x + s];
        __syncthreads();
    }
    if (threadIdx.x == 0) {
        float klv = 0.f;
        for (int i = 0; i < 27; ++i) {
            float sp = softplusf_(scale[i]);
            float m = loc[i];
            klv += -logf(sp) + 0.5f * (sp * sp + m * m) - 0.5f;
        }
        out[0] = (float)(sm[0] / (double)BB + (double)LL * (double)klv);
    }
}

extern "C" void kernel_launch(void* const* d_in, const int* in_sizes, int n_in,
                              void* d_out, int out_size, void* d_ws, size_t ws_size,
                              hipStream_t stream) {
    const float* x = (const float*)d_in[0];
    const float* loc = (const float*)d_in[1];
    const float* scale = (const float*)d_in[2];
    const float* eps = (const float*)d_in[3];
    float* out = (float*)d_out;

    char* ws = (char*)d_ws;
    double* partials = (double*)(ws + 1024);          // 4096*8 -> ends 33792
    float* es4 = (float*)(ws + 131072);               // 524288  -> 655360
    float* es3 = (float*)(ws + 655360);               // 2097152 -> 2752512
    float* es2 = (float*)(ws + 2752512);              // 8388608 -> 11141120
    (void)in_sizes; (void)n_in; (void)out_size;

    const size_t SINGLE_NEED = 55181312ull;
    if (ws_size >= SINGLE_NEED) {
        __half* xh2 = (__half*)(ws + 11141120);       // 25165824 -> 36306944
        __half* xh4 = (__half*)(ws + 36306944);       // 12582912 -> 48889856
        __half* xh8 = (__half*)(ws + 48889856);       // 6291456  -> 55181312
        hpass_kernel<<<BB * HH / 4, 256, 0, stream>>>(x, xh2, xh4, xh8);
        levels_kernel<<<7168, 256, 0, stream>>>(xh2, xh4, xh8, loc, scale, eps, es2, es3, es4, 0);
    } else {
        __half* xh4 = (__half*)(ws + 11141120);
        __half* xh8 = (__half*)(ws + 23724032);
        __half* xh2 = (__half*)(ws + 11141120);
        hpass_kernel<<<BB * HH / 4, 256, 0, stream>>>(x, nullptr, xh4, xh8);
        levels_kernel<<<3072, 256, 0, stream>>>(nullptr, xh4, xh8, loc, scale, eps, es2, es3, es4, 4096);
        hpass_kernel<<<BB * HH / 4, 256, 0, stream>>>(x, xh2, nullptr, nullptr);
        levels_kernel<<<4096, 256, 0, stream>>>(xh2, nullptr, nullptr, loc, scale, eps, es2, es3, es4, 0);
    }

    fused_kernel<<<dim3(8, 16, BB), 256, 0, stream>>>(x, loc, scale, eps, es2, es3, es4, partials);
    final_kernel<<<1, 1024, 0, stream>>>(partials, 4096, loc, scale, out);
}

// Round 14
// 102.478 us; speedup vs baseline: 2.0952x; 1.3465x over previous
//
#include <hip/hip_runtime.h>
#include <hip/hip_fp16.h>
#include <math.h>

#define BB 32
#define HH 512
#define WW 512
#define CC 3
#define LL 4

typedef _Float16 h2_t __attribute__((ext_vector_type(2)));

static __device__ __forceinline__ float softplusf_(float x) {
    if (x > 20.f) return x;
    return log1pf(expf(x));
}
static __device__ __forceinline__ int iclamp_(int v, int lo, int hi) {
    return v < lo ? lo : (v > hi ? hi : v);
}

// ---------------- prep: normalized per-level kernels + KL ----------------
__global__ void prep_kernel(const float* __restrict__ loc, const float* __restrict__ scale,
                            const float* __restrict__ eps, float* __restrict__ knorm,
                            double* __restrict__ kl_out) {
    int tid = threadIdx.x;   // 64 threads
    float klv = 0.f;
    if (tid < 27) {
        float s = softplusf_(scale[tid]);
        float m = loc[tid];
        klv = -logf(s) + 0.5f * (s * s + m * m) - 0.5f;
    }
    #pragma unroll
    for (int off = 32; off; off >>= 1) klv += __shfl_down(klv, off);
    if (tid == 0) *kl_out = (double)klv;
    if (tid < 12) {
        int l = tid / 3;
        int c = tid - l * 3;
        float v[9];
        float sum = 0.f;
        #pragma unroll
        for (int t = 0; t < 9; ++t) {
            int idx = t * 3 + c;
            float s = softplusf_(scale[idx]);
            float val = loc[idx] + s * eps[l * 27 + idx];
            if (t == 4) val = 0.f;
            v[t] = val;
            sum += val;
        }
        float denom = sum + 1e-7f;
        #pragma unroll
        for (int t = 0; t < 9; ++t)
            knorm[l * 27 + t * 3 + c] = v[t] / denom;
    }
}

// ---------------- horizontal downsample: fp16 planes + constant-offset dot2 ----------------
#define PSH 544                  // plane stride in halves
#define RESC 1.1428571428571428f // 1/0.875

__global__ void hpass_kernel(const float* __restrict__ x, __half* __restrict__ xh2,
                             __half* __restrict__ xh4, __half* __restrict__ xh8) {
    __shared__ __align__(16) __half planes[4 * 3 * PSH];
    const int tid = threadIdx.x;
    const int lane = tid & 63;
    const int wv = tid >> 6;
    const int bh = blockIdx.x * 4 + wv;         // row id: b*512 + h
    __half* pl = planes + wv * (3 * PSH);

    const float4* src = (const float4*)(x + bh * (WW * CC));
    #pragma unroll
    for (int s = 0; s < 6; ++s) {
        int i = lane + (s << 6);                // float4 index 0..383
        float4 v = src[i];
        int g = i << 2;
        int j = g / 3;
        int c = g - j * 3;
        float e[4] = {v.x, v.y, v.z, v.w};
        #pragma unroll
        for (int u = 0; u < 4; ++u) {
            pl[c * PSH + 17 + j] = __float2half_rn(e[u]);
            ++c;
            if (c == 3) { c = 0; ++j; }
        }
    }
    {
        int t = lane;
        if (t < 96) {
            int pp = t >> 5, k = t & 31;
            int hi = (k < 17) ? k : (512 + k);
            pl[pp * PSH + hi] = __float2half_rn(0.f);
        }
        t = lane + 64;
        if (t < 96) {
            int pp = t >> 5, k = t & 31;
            int hi = (k < 17) ? k : (512 + k);
            pl[pp * PSH + hi] = __float2half_rn(0.f);
        }
    }
    asm volatile("s_waitcnt lgkmcnt(0)" ::: "memory");

    if (xh2) {
        const h2_t P0 = {(_Float16)0.125f, (_Float16)0.375f};
        const h2_t P1 = {(_Float16)0.375f, (_Float16)0.125f};
        __half* o2 = xh2 + bh * 768;
        #pragma unroll
        for (int s = 0; s < 4; ++s) {
            int ow = lane + (s << 6);
            float res[3];
            #pragma unroll
            for (int c = 0; c < 3; ++c) {
                const __half* p = pl + c * PSH;
                int hb2 = 2 * lane + 128 * s + 16;
                h2_t v0 = *(const h2_t*)&p[hb2];
                h2_t v1 = *(const h2_t*)&p[hb2 + 2];
                float a = __builtin_amdgcn_fdot2(v0, P0, 0.f, false);
                a = __builtin_amdgcn_fdot2(v1, P1, a, false);
                res[c] = a;
            }
            if (s == 0 && lane == 0) { res[0] *= RESC; res[1] *= RESC; res[2] *= RESC; }
            if (s == 3 && lane == 63) { res[0] *= RESC; res[1] *= RESC; res[2] *= RESC; }
            o2[ow * 3 + 0] = __float2half_rn(res[0]);
            o2[ow * 3 + 1] = __float2half_rn(res[1]);
            o2[ow * 3 + 2] = __float2half_rn(res[2]);
        }
    }
    if (xh4) {
        const h2_t P0 = {(_Float16)0.f,      (_Float16)0.03125f};
        const h2_t P1 = {(_Float16)0.09375f, (_Float16)0.15625f};
        const h2_t P2 = {(_Float16)0.21875f, (_Float16)0.21875f};
        const h2_t P3 = {(_Float16)0.15625f, (_Float16)0.09375f};
        const h2_t P4 = {(_Float16)0.03125f, (_Float16)0.f};
        __half* o4 = xh4 + bh * 384;
        #pragma unroll
        for (int s = 0; s < 2; ++s) {
            int ow = lane + (s << 6);
            float res[3];
            #pragma unroll
            for (int c = 0; c < 3; ++c) {
                const __half* p = pl + c * PSH;
                int hb2 = 4 * lane + 256 * s + 14;
                float a = __builtin_amdgcn_fdot2(*(const h2_t*)&p[hb2], P0, 0.f, false);
                a = __builtin_amdgcn_fdot2(*(const h2_t*)&p[hb2 + 2], P1, a, false);
                a = __builtin_amdgcn_fdot2(*(const h2_t*)&p[hb2 + 4], P2, a, false);
                a = __builtin_amdgcn_fdot2(*(const h2_t*)&p[hb2 + 6], P3, a, false);
                a = __builtin_amdgcn_fdot2(*(const h2_t*)&p[hb2 + 8], P4, a, false);
                res[c] = a;
            }
            if (s == 0 && lane == 0) { res[0] *= RESC; res[1] *= RESC; res[2] *= RESC; }
            if (s == 1 && lane == 63) { res[0] *= RESC; res[1] *= RESC; res[2] *= RESC; }
            o4[ow * 3 + 0] = __float2half_rn(res[0]);
            o4[ow * 3 + 1] = __float2half_rn(res[1]);
            o4[ow * 3 + 2] = __float2half_rn(res[2]);
        }
    }
    if (xh8) {
        const h2_t Q0 = {(_Float16)0.f,         (_Float16)0.0078125f};
        const h2_t Q1 = {(_Float16)0.0234375f,  (_Float16)0.0390625f};
        const h2_t Q2 = {(_Float16)0.0546875f,  (_Float16)0.0703125f};
        const h2_t Q3 = {(_Float16)0.0859375f,  (_Float16)0.1015625f};
        const h2_t Q4 = {(_Float16)0.1171875f,  (_Float16)0.1171875f};
        const h2_t Q5 = {(_Float16)0.1015625f,  (_Float16)0.0859375f};
        const h2_t Q6 = {(_Float16)0.0703125f,  (_Float16)0.0546875f};
        const h2_t Q7 = {(_Float16)0.0390625f,  (_Float16)0.0234375f};
        const h2_t Q8 = {(_Float16)0.0078125f,  (_Float16)0.f};
        __half* o8 = xh8 + bh * 192;
        int ow = lane;
        float res[3];
        #pragma unroll
        for (int c = 0; c < 3; ++c) {
            const __half* p = pl + c * PSH;
            int hb2 = 8 * lane + 12;
            float a = __builtin_amdgcn_fdot2(*(const h2_t*)&p[hb2], Q0, 0.f, false);
            a = __builtin_amdgcn_fdot2(*(const h2_t*)&p[hb2 + 2], Q1, a, false);
            a = __builtin_amdgcn_fdot2(*(const h2_t*)&p[hb2 + 4], Q2, a, false);
            a = __builtin_amdgcn_fdot2(*(const h2_t*)&p[hb2 + 6], Q3, a, false);
            a = __builtin_amdgcn_fdot2(*(const h2_t*)&p[hb2 + 8], Q4, a, false);
            a = __builtin_amdgcn_fdot2(*(const h2_t*)&p[hb2 + 10], Q5, a, false);
            a = __builtin_amdgcn_fdot2(*(const h2_t*)&p[hb2 + 12], Q6, a, false);
            a = __builtin_amdgcn_fdot2(*(const h2_t*)&p[hb2 + 14], Q7, a, false);
            a = __builtin_amdgcn_fdot2(*(const h2_t*)&p[hb2 + 16], Q8, a, false);
            res[c] = a;
        }
        if (lane == 0) { res[0] *= RESC; res[1] *= RESC; res[2] *= RESC; }
        if (lane == 63) { res[0] *= RESC; res[1] *= RESC; res[2] *= RESC; }
        o8[ow * 3 + 0] = __float2half_rn(res[0]);
        o8[ow * 3 + 1] = __float2half_rn(res[1]);
        o8[ow * 3 + 2] = __float2half_rn(res[2]);
    }
}

// ---------------- per-level: LDS-staged vertical pass + conv + channel-sum ----------------
template <int F, int THB>
static __device__ __forceinline__ void level_body(const __half* __restrict__ xh,
                                                  const float* __restrict__ knorm_all, int lvl,
                                                  float* __restrict__ es, int bx, int by, int b,
                                                  char* smem_raw) {
    constexpr int TH = HH / F, TW = WW / F, TW3 = TW * 3, TAPS = 2 * F;
    constexpr int RS = (THB + 3) * F;
    constexpr int DR = THB + 2;
    __half* stg = (__half*)smem_raw;                          // [RS][108]
    float* dst = (float*)(smem_raw + RS * 108 * 2);           // [DR][108]
    float* wvv = dst + DR * 108;                              // [DR][TAPS]
    float* kn = wvv + DR * TAPS;                              // [27]
    int owb = bx * 32, ohb = by * THB;
    int tid = threadIdx.x;
    if (tid < 27) kn[tid] = knorm_all[lvl * 27 + tid];
    if (tid >= 32 && tid < 32 + DR) {
        int r = tid - 32;
        int oh = ohb - 1 + r;
        if (oh < 0 || oh >= TH) {
            #pragma unroll
            for (int k = 0; k < TAPS; ++k) wvv[r * TAPS + k] = 0.f;
        } else {
            float sfh = (oh + 0.5f) * F - 0.5f;
            int j0 = oh * F - F / 2;
            float tmp[TAPS]; float s = 0.f;
            #pragma unroll
            for (int k = 0; k < TAPS; ++k) {
                int j = j0 + k;
                float w = (j >= 0 && j < HH) ? (1.f - fabsf(j - sfh) * (1.0f / F)) : 0.f;
                tmp[k] = w; s += w;
            }
            float inv = 1.f / s;
            #pragma unroll
            for (int k = 0; k < TAPS; ++k) wvv[r * TAPS + k] = tmp[k] * inv;
        }
    }
    int jmin = (ohb - 1) * F - F / 2;
    int cb = owb * 3 - 4;
    bool fast = (cb >= 0) && (cb + 108 <= TW3);
    const __half* xb = xh + b * (HH * TW3);
    for (int i = tid; i < RS * 27; i += 256) {
        int r = i / 27;
        int c4 = (i - r * 27) * 4;
        int jh = iclamp_(jmin + r, 0, HH - 1);
        const __half* rp = xb + jh * TW3;
        if (fast) {
            *(ushort4*)&stg[r * 108 + c4] = *(const ushort4*)(rp + cb + c4);
        } else {
            #pragma unroll
            for (int u = 0; u < 4; ++u) {
                int col = iclamp_(cb + c4 + u, 0, TW3 - 1);
                stg[r * 108 + c4 + u] = rp[col];
            }
        }
    }
    __syncthreads();
    for (int i = tid; i < DR * 27; i += 256) {
        int r = i / 27;
        int c4 = (i - r * 27) * 4;
        int gc = cb + c4;
        float v0 = 0, v1 = 0, v2 = 0, v3 = 0;
        if ((unsigned)gc < (unsigned)TW3) {
            const __half* sp = &stg[r * F * 108 + c4];
            const float* wr = &wvv[r * TAPS];
            #pragma unroll
            for (int k = 0; k < TAPS; ++k) {
                float wk = wr[k];
                const __half2* h2 = (const __half2*)(sp + k * 108);
                float2 f0 = __half22float2(h2[0]);
                float2 f1 = __half22float2(h2[1]);
                v0 += wk * f0.x; v1 += wk * f0.y;
                v2 += wk * f1.x; v3 += wk * f1.y;
            }
        }
        float4 q; q.x = v0; q.y = v1; q.z = v2; q.w = v3;
        *(float4*)&dst[r * 108 + c4] = q;
    }
    __syncthreads();
    for (int i = tid; i < THB * 32; i += 256) {
        int wl = i & 31, hl = i >> 5;
        int base = hl * 108 + wl * 3 + 1;
        float e = 0.f;
        #pragma unroll
        for (int c = 0; c < 3; ++c) {
            float conv = 0.f;
            #pragma unroll
            for (int dh = 0; dh < 3; ++dh)
                #pragma unroll
                for (int dw = 0; dw < 3; ++dw)
                    conv += kn[(dh * 3 + dw) * 3 + c] * dst[base + dh * 108 + dw * 3 + c];
            e += dst[base + 108 + 3 + c] - conv;
        }
        es[b * (TH * TW) + (ohb + hl) * TW + owb + wl] = e;
    }
}

__global__ void levels_kernel(const __half* __restrict__ xh2, const __half* __restrict__ xh4,
                              const __half* __restrict__ xh8, const float* __restrict__ knorm,
                              float* __restrict__ es2, float* __restrict__ es3,
                              float* __restrict__ es4, int block_base) {
    __shared__ __align__(16) char smem[16896];
    int vb = blockIdx.x + block_base;
    if (vb < 4096) {
        level_body<2, 16>(xh2, knorm, 1, es2, vb & 7, (vb >> 3) & 15, vb >> 7, smem);
    } else if (vb < 6144) {
        int l = vb - 4096;
        level_body<4, 8>(xh4, knorm, 2, es3, l & 3, (l >> 2) & 15, l >> 6, smem);
    } else {
        int l = vb - 6144;
        level_body<8, 4>(xh8, knorm, 3, es4, l & 1, (l >> 1) & 15, l >> 5, smem);
    }
}

// ---------------- fused: 32x64 tile, channel planes stride 67, 8 px/thread ----------------
#define F2PS 67
#define F2PC (34 * F2PS)   // 2278
__global__ void __launch_bounds__(256, 4)
fused_kernel(const float* __restrict__ x, const float* __restrict__ knorm,
             const float* __restrict__ es2, const float* __restrict__ es3,
             const float* __restrict__ es4, double* __restrict__ partials) {
    __shared__ __align__(16) float planes[3 * F2PC];   // 27336 B
    __shared__ float e2t[18 * 35];
    __shared__ float e3t[10 * 19];
    __shared__ float e4t[6 * 11];
    __shared__ float kn[27];
    __shared__ float smf[4];
    int b = blockIdx.z;
    int hb = blockIdx.y * 32, wb = blockIdx.x * 64;
    int tid = threadIdx.x;
    if (tid < 27) kn[tid] = knorm[tid];
    const float* xb = x + b * (HH * WW * CC);
    const int cb = wb * 3 - 3;     // first needed float (pixel wb-1)
    const int cb2 = wb * 3 - 4;    // 16B-aligned chunk base
    for (int i = tid; i < 34 * 50; i += 256) {
        int r = i / 50;
        int k = i - r * 50;
        int gh = hb - 1 + r;
        bool ghv = (unsigned)gh < (unsigned)HH;
        int g0 = cb2 + 4 * k;
        float vv[4] = {0.f, 0.f, 0.f, 0.f};
        if (ghv) {
            const float* rp = xb + gh * (WW * CC);
            if (g0 >= 0 && g0 + 4 <= WW * CC) {
                float4 v = *(const float4*)(rp + g0);
                vv[0] = v.x; vv[1] = v.y; vv[2] = v.z; vv[3] = v.w;
            } else {
                #pragma unroll
                for (int u = 0; u < 4; ++u) {
                    int g = g0 + u;
                    vv[u] = ((unsigned)g < (unsigned)(WW * CC)) ? rp[g] : 0.f;
                }
            }
        }
        #pragma unroll
        for (int u = 0; u < 4; ++u) {
            int g = g0 + u;
            if (g >= cb && g < cb + 198) {
                int gq = g + 3;
                int j = gq / 3;                 // pixel + 1
                int c = gq - j * 3;
                int col = j - wb;               // in [0,66)
                planes[c * F2PC + r * F2PS + col] = vv[u];
            }
        }
    }
    {
        const float* e2b = es2 + b * (256 * 256);
        int h0 = hb / 2 - 1, w0 = wb / 2 - 1;
        for (int i = tid; i < 18 * 34; i += 256) {
            int r = i / 34, c = i - r * 34;
            int gh = iclamp_(h0 + r, 0, 255);
            int gw = iclamp_(w0 + c, 0, 255);
            e2t[r * 35 + c] = e2b[gh * 256 + gw];
        }
        const float* e3b = es3 + b * (128 * 128);
        int h03 = hb / 4 - 1, w03 = wb / 4 - 1;
        if (tid < 180) {
            int r = tid / 18, c = tid - r * 18;
            int gh = iclamp_(h03 + r, 0, 127);
            int gw = iclamp_(w03 + c, 0, 127);
            e3t[r * 19 + c] = e3b[gh * 128 + gw];
        }
        const float* e4b = es4 + b * (64 * 64);
        if (tid < 60) {
            int r = tid / 10, c = tid - r * 10;
            int gh = iclamp_(hb / 8 - 1 + r, 0, 63);
            int gw = iclamp_(wb / 8 - 1 + c, 0, 63);
            e4t[r * 11 + c] = e4b[gh * 64 + gw];
        }
    }
    __syncthreads();

    int q = tid >> 3;        // output row 0..31
    int a = tid & 7;         // col group: 8 px at local cols 8a..8a+7
    float cv[8] = {0.f, 0.f, 0.f, 0.f, 0.f, 0.f, 0.f, 0.f};
    float ce[8] = {0.f, 0.f, 0.f, 0.f, 0.f, 0.f, 0.f, 0.f};
    #pragma unroll
    for (int c = 0; c < 3; ++c) {
        const float* P = planes + c * F2PC;
        #pragma unroll
        for (int dh = 0; dh < 3; ++dh) {
            const float* r0 = P + (q + dh) * F2PS + 8 * a;
            float w[10];
            #pragma unroll
            for (int t = 0; t < 10; ++t) w[t] = r0[t];
            float k0 = kn[dh * 9 + c], k1 = kn[dh * 9 + 3 + c], k2 = kn[dh * 9 + 6 + c];
            #pragma unroll
            for (int p = 0; p < 8; ++p)
                cv[p] += k0 * w[p] + k1 * w[p + 1] + k2 * w[p + 2];
            if (dh == 1) {
                #pragma unroll
                for (int p = 0; p < 8; ++p) ce[p] += w[p + 1];
            }
        }
    }
    float e[8];
    #pragma unroll
    for (int p = 0; p < 8; ++p) e[p] = ce[p] - cv[p];

    int n2 = q & 1;   float fh2 = n2 ? 0.25f : 0.75f;               int rh2 = (q >> 1) + n2;
    int n4 = q & 3;   float fh4 = ((n4 + 2) & 3) * 0.25f + 0.125f;  int rh4 = (q >> 2) + (n4 < 2 ? 0 : 1);
    int n8 = q & 7;   float fh8 = ((n8 + 4) & 7) * 0.125f + 0.0625f; int rh8 = (q >> 3) + (n8 < 4 ? 0 : 1);
    {   // L2: 6 taps per row at cols 4a..4a+5
        const float* r0 = &e2t[rh2 * 35 + 4 * a];
        const float* r1 = r0 + 35;
        float t0 = r0[0], t1 = r0[1], t2 = r0[2], t3 = r0[3], t4 = r0[4], t5 = r0[5];
        float b0 = r1[0], b1 = r1[1], b2 = r1[2], b3 = r1[3], b4 = r1[4], b5 = r1[5];
        float top, bot;
        top = t0 + 0.75f * (t1 - t0); bot = b0 + 0.75f * (b1 - b0); e[0] += top + fh2 * (bot - top);
        top = t1 + 0.25f * (t2 - t1); bot = b1 + 0.25f * (b2 - b1); e[1] += top + fh2 * (bot - top);
        top = t1 + 0.75f * (t2 - t1); bot = b1 + 0.75f * (b2 - b1); e[2] += top + fh2 * (bot - top);
        top = t2 + 0.25f * (t3 - t2); bot = b2 + 0.25f * (b3 - b2); e[3] += top + fh2 * (bot - top);
        top = t2 + 0.75f * (t3 - t2); bot = b2 + 0.75f * (b3 - b2); e[4] += top + fh2 * (bot - top);
        top = t3 + 0.25f * (t4 - t3); bot = b3 + 0.25f * (b4 - b3); e[5] += top + fh2 * (bot - top);
        top = t3 + 0.75f * (t4 - t3); bot = b3 + 0.75f * (b4 - b3); e[6] += top + fh2 * (bot - top);
        top = t4 + 0.25f * (t5 - t4); bot = b4 + 0.25f * (b5 - b4); e[7] += top + fh2 * (bot - top);
    }
    {   // L3: 4 taps per row at cols 2a..2a+3
        const float* r0 = &e3t[rh4 * 19 + 2 * a];
        const float* r1 = r0 + 19;
        float t0 = r0[0], t1 = r0[1], t2 = r0[2], t3 = r0[3];
        float b0 = r1[0], b1 = r1[1], b2 = r1[2], b3 = r1[3];
        float top, bot;
        top = t0 + 0.625f * (t1 - t0); bot = b0 + 0.625f * (b1 - b0); e[0] += top + fh4 * (bot - top);
        top = t0 + 0.875f * (t1 - t0); bot = b0 + 0.875f * (b1 - b0); e[1] += top + fh4 * (bot - top);
        top = t1 + 0.125f * (t2 - t1); bot = b1 + 0.125f * (b2 - b1); e[2] += top + fh4 * (bot - top);
        top = t1 + 0.375f * (t2 - t1); bot = b1 + 0.375f * (b2 - b1); e[3] += top + fh4 * (bot - top);
        top = t1 + 0.625f * (t2 - t1); bot = b1 + 0.625f * (b2 - b1); e[4] += top + fh4 * (bot - top);
        top = t1 + 0.875f * (t2 - t1); bot = b1 + 0.875f * (b2 - b1); e[5] += top + fh4 * (bot - top);
        top = t2 + 0.125f * (t3 - t2); bot = b2 + 0.125f * (b3 - b2); e[6] += top + fh4 * (bot - top);
        top = t2 + 0.375f * (t3 - t2); bot = b2 + 0.375f * (b3 - b2); e[7] += top + fh4 * (bot - top);
    }
    {   // L4: 3 taps per row at cols a..a+2
        const float* r0 = &e4t[rh8 * 11 + a];
        const float* r1 = r0 + 11;
        float t0 = r0[0], t1 = r0[1], t2 = r0[2];
        float b0 = r1[0], b1 = r1[1], b2 = r1[2];
        #pragma unroll
        for (int p = 0; p < 4; ++p) {
            float fw = 0.5625f + 0.125f * p;
            float top = t0 + fw * (t1 - t0);
            float bot = b0 + fw * (b1 - b0);
            e[p] += top + fh8 * (bot - top);
        }
        #pragma unroll
        for (int p = 4; p < 8; ++p) {
            float fw = 0.0625f + 0.125f * (p - 4);
            float top = t1 + fw * (t2 - t1);
            float bot = b1 + fw * (b2 - b1);
            e[p] += top + fh8 * (bot - top);
        }
    }
    float acc = 0.f;
    #pragma unroll
    for (int p = 0; p < 8; ++p) acc += e[p] * e[p];
    #pragma unroll
    for (int off = 32; off; off >>= 1) acc += __shfl_down(acc, off);
    if ((tid & 63) == 0) smf[tid >> 6] = acc;
    __syncthreads();
    if (tid == 0) {
        double s = (double)smf[0] + (double)smf[1] + (double)smf[2] + (double)smf[3];
        partials[(b * 16 + blockIdx.y) * 8 + blockIdx.x] = s;
    }
}

__global__ void final_kernel(const double* __restrict__ partials, int n,
                             const double* __restrict__ kl, float* __restrict__ out) {
    __shared__ double sm[1024];
    double acc = 0.0;
    for (int i = threadIdx.x; i < n; i += 1024) acc += partials[i];
    sm[threadIdx.x] = acc;
    __syncthreads();
    for (int s = 512; s > 0; s >>= 1) {
        if (threadIdx.x < (unsigned)s) sm[threadIdx.x] += sm[threadIdx.x + s];
        __syncthreads();
    }
    if (threadIdx.x == 0) out[0] = (float)(sm[0] / (double)BB + (double)LL * kl[0]);
}

extern "C" void kernel_launch(void* const* d_in, const int* in_sizes, int n_in,
                              void* d_out, int out_size, void* d_ws, size_t ws_size,
                              hipStream_t stream) {
    const float* x = (const float*)d_in[0];
    const float* loc = (const float*)d_in[1];
    const float* scale = (const float*)d_in[2];
    const float* eps = (const float*)d_in[3];
    float* out = (float*)d_out;

    char* ws = (char*)d_ws;
    float* knorm = (float*)(ws + 0);
    double* kl = (double*)(ws + 512);
    double* partials = (double*)(ws + 1024);          // 4096*8 -> ends 33792
    float* es4 = (float*)(ws + 131072);               // 524288  -> 655360
    float* es3 = (float*)(ws + 655360);               // 2097152 -> 2752512
    float* es2 = (float*)(ws + 2752512);              // 8388608 -> 11141120
    (void)in_sizes; (void)n_in; (void)out_size;

    prep_kernel<<<1, 64, 0, stream>>>(loc, scale, eps, knorm, kl);

    const size_t SINGLE_NEED = 55181312ull;
    if (ws_size >= SINGLE_NEED) {
        __half* xh2 = (__half*)(ws + 11141120);       // 25165824 -> 36306944
        __half* xh4 = (__half*)(ws + 36306944);       // 12582912 -> 48889856
        __half* xh8 = (__half*)(ws + 48889856);       // 6291456  -> 55181312
        hpass_kernel<<<BB * HH / 4, 256, 0, stream>>>(x, xh2, xh4, xh8);
        levels_kernel<<<7168, 256, 0, stream>>>(xh2, xh4, xh8, knorm, es2, es3, es4, 0);
    } else {
        // split path: xh4+xh8 first, then xh2 reuses the same region (<= 36.3 MB peak)
        __half* xh4 = (__half*)(ws + 11141120);
        __half* xh8 = (__half*)(ws + 23724032);
        __half* xh2 = (__half*)(ws + 11141120);
        hpass_kernel<<<BB * HH / 4, 256, 0, stream>>>(x, nullptr, xh4, xh8);
        levels_kernel<<<3072, 256, 0, stream>>>(nullptr, xh4, xh8, knorm, es2, es3, es4, 4096);
        hpass_kernel<<<BB * HH / 4, 256, 0, stream>>>(x, xh2, nullptr, nullptr);
        levels_kernel<<<4096, 256, 0, stream>>>(xh2, nullptr, nullptr, knorm, es2, es3, es4, 0);
    }

    fused_kernel<<<dim3(8, 16, BB), 256, 0, stream>>>(x, knorm, es2, es3, es4, partials);
    final_kernel<<<1, 1024, 0, stream>>>(partials, 4096, kl, out);
}